// Round 20
// baseline (46.025 us; speedup 1.0000x reference)
//
#include <hip/hip_runtime.h>
#include <hip/hip_bf16.h>
#include <math.h>

#define BB 16
#define DD 128
#define NN 4096
#define KK 1024
// Positivity shift folded into e2': m = e2 + CADD - 2<z,e> = d^2 + (CADD - z^2).
// z^2 ~ chi2(128): max over 65k cols ~ 205 << 320 -> m > 0 always. Key quant
// at m<=~740 is <=0.125; TAU covers flip-window + quantization.
#define CADD 320.0f
#define TAU 0.45f

typedef __attribute__((ext_vector_type(8))) short short8;
typedef __attribute__((ext_vector_type(4))) float f32x4;

static __device__ __forceinline__ unsigned short f32_bf16_rne(float f) {
    unsigned u = __float_as_uint(f);
    u += 0x7FFF + ((u >> 16) & 1);
    return (unsigned short)(u >> 16);
}
static __device__ __forceinline__ unsigned umin32(unsigned a, unsigned b) { return a < b ? a : b; }
static __device__ __forceinline__ unsigned umax32(unsigned a, unsigned b) { return a > b ? a : b; }
static __device__ __forceinline__ unsigned umed3(unsigned a, unsigned b, unsigned c) {
    unsigned d;
    asm("v_med3_u32 %0, %1, %2, %3" : "=v"(d) : "v"(a), "v"(b), "v"(c));
    return d;
}

// ---------------------------------------------------------------------------
// e2'[k] = ||emb[k]||^2 + CADD  (f32)
// ---------------------------------------------------------------------------
__global__ void emb_sq_kernel(const float* __restrict__ emb,
                              float* __restrict__ e2) {
    int k = blockIdx.x * 256 + threadIdx.x;
    if (k >= KK) return;
    const float4* row = reinterpret_cast<const float4*>(emb + (size_t)k * DD);
    float a0 = 0.f, a1 = 0.f, a2 = 0.f, a3 = 0.f;
#pragma unroll
    for (int i = 0; i < DD / 16; ++i) {
        float4 v0 = row[i * 4 + 0];
        float4 v1 = row[i * 4 + 1];
        float4 v2 = row[i * 4 + 2];
        float4 v3 = row[i * 4 + 3];
        a0 += v0.x * v0.x + v0.y * v0.y + v0.z * v0.z + v0.w * v0.w;
        a1 += v1.x * v1.x + v1.y * v1.y + v1.z * v1.z + v1.w * v1.w;
        a2 += v2.x * v2.x + v2.y * v2.y + v2.z * v2.z + v2.w * v2.w;
        a3 += v3.x * v3.x + v3.y * v3.y + v3.z * v3.z + v3.w * v3.w;
    }
    e2[k] = (a0 + a1) + (a2 + a3) + CADD;
}

// ---------------------------------------------------------------------------
// Pack (-2 * emb) as SINGLE bf16 in MFMA A-fragment order (256 KB).
// Fragment (t, s, lane): k = t*16 + (lane&15), d = s*32 + (lane>>4)*8 + j.
// ---------------------------------------------------------------------------
__global__ void emb_pack_kernel(const float* __restrict__ emb,
                                short* __restrict__ epk) {
    int g = blockIdx.x * 256 + threadIdx.x;     // 16384 fragment-slots
    int lane = g & 63;
    int s    = (g >> 6) & 3;
    int t    = g >> 8;
    int k = t * 16 + (lane & 15);
    int d = s * 32 + ((lane >> 4) & 3) * 8;
    const float* src = emb + (size_t)k * DD + d;
    short8 h;
#pragma unroll
    for (int j = 0; j < 8; ++j) h[j] = (short)f32_bf16_rne(-2.0f * src[j]);
    *reinterpret_cast<short8*>(epk + (size_t)g * 8) = h;
}

// CE on packed u32 keys: a <- min, b <- max (2 VALU, no vcc)
#define CEU(a, b) { unsigned lo_ = umin32(a, b), hi_ = umax32(a, b); (a) = lo_; (b) = hi_; }
// merge two ascending-4 key lists; lowest 4 end sorted in A1..A4
#define MRG9(A1, A2, A3, A4, B1, B2, B3, B4) \
    CEU(A1, B1) CEU(A2, B2) CEU(A3, B3) CEU(A4, B4) \
    CEU(A3, B1) CEU(A4, B2) \
    CEU(A2, A3) \
    CEU(A4, B1) \
    CEU(A3, A4)

// ---------------------------------------------------------------------------
// Round-20 (stream-sharing at fixed intensity): block = 128 cols, 8 waves =
// 2 col-halves x 4 k-quarters; wave = 64 cols x 256 k (r19's intensity).
// The two waves on a k-quarter share ONE epk stream -> 8 streams/CU
// (2 blocks x 4) vs r19's 16; 8 x 4KB tiles ~ L1 capacity. Occupancy equal
// to r19 (16 waves/CU, (512,4) = the proven 128-reg budget). Key/trigger/
// refine/epilogue semantics as r12-r19 (absmax 0 x9).
// ---------------------------------------------------------------------------
__global__ __launch_bounds__(512, 4)
void vq_mfma(const float* __restrict__ ze, const float* __restrict__ emb,
             const short* __restrict__ epk, const float* __restrict__ e2,
             float* __restrict__ out) {
    // union: z-stage frags (32 KB) -> ew[128][65] (33.3 KB) after main loop
    __shared__ __align__(16) char ubuf[128 * 65 * 4];        // 33280 B
    __shared__ unsigned kbuf[4][128][4];                     // 8 KB
    __shared__ int winner_s[128];
    __shared__ int rlist[128];
    __shared__ int rcnt0, rcnt1;

    short* zstage = reinterpret_cast<short*>(ubuf);          // 16384 shorts

    const int tid  = threadIdx.x;
    const int lane = tid & 63;
    const int wave = tid >> 6;                    // 0..7
    const int colhalf = wave & 1;                 // main-loop col half
    const int kq      = wave >> 1;                // main-loop k quarter
    const int b    = blockIdx.x >> 5;             // 32 blocks per batch entry
    const int n0b  = (blockIdx.x & 31) * 128;     // block's 128-col base
    const float* zb = ze + (size_t)b * DD * NN;

    const int nq = lane & 15;
    const int dq = (lane >> 4) & 3;

    // ---- cooperative z staging: wave w stages cgs {(w>>2)*4..+3}, s = w&3
#pragma unroll
    for (int c4 = 0; c4 < 4; ++c4) {
        const int cg  = (wave >> 2) * 4 + c4;     // 0..7
        const int col = n0b + cg * 16 + nq;
        const int d0  = (wave & 3) * 32 + dq * 8;
        const float* zp = zb + (size_t)d0 * NN + col;
        short8 h;
#pragma unroll
        for (int j = 0; j < 8; ++j) h[j] = (short)f32_bf16_rne(zp[(size_t)j * NN]);
        *reinterpret_cast<short8*>(zstage + ((cg * 4 + (wave & 3)) * 64 + lane) * 8) = h;
    }
    __syncthreads();

    // ---- zf frags for this wave's 64 cols (cg = colhalf*4 + cg') ----
    short8 zf[4][4];
#pragma unroll
    for (int cgp = 0; cgp < 4; ++cgp)
#pragma unroll
        for (int s = 0; s < 4; ++s)
            zf[cgp][s] = *reinterpret_cast<const short8*>(
                zstage + (((colhalf * 4 + cgp) * 4 + s) * 64 + lane) * 8);
    __syncthreads();               // zstage dead; ubuf reused as ew later

    // per-cg top-2 packed keys (ascending)
    unsigned K1[4], K2[4];
#pragma unroll
    for (int cg = 0; cg < 4; ++cg) { K1[cg] = K2[cg] = 0xFFFFFFFFu; }

    const int t0 = kq * 16;                       // this wave's 16 k-tiles
    const short* ep  = epk + (size_t)(t0 * 4) * 512 + (size_t)lane * 8;
    const float* e2p = e2 + t0 * 16 + dq * 4;
    unsigned kb = (unsigned)(t0 * 16 + dq * 4);

#pragma unroll 2
    for (int tt = 0; tt < 16; ++tt) {
        const short8 a0 = *reinterpret_cast<const short8*>(ep);
        const short8 a1 = *reinterpret_cast<const short8*>(ep + 512);
        const short8 a2 = *reinterpret_cast<const short8*>(ep + 1024);
        const short8 a3 = *reinterpret_cast<const short8*>(ep + 1536);
        const float4 ev = *reinterpret_cast<const float4*>(e2p);

        f32x4 acc0 = {ev.x, ev.y, ev.z, ev.w};   // e2' copy (CADD pre-folded)
        f32x4 acc1 = acc0, acc2 = acc0, acc3 = acc0;
#define STEP(AF, S) \
        acc0 = __builtin_amdgcn_mfma_f32_16x16x32_bf16(AF, zf[0][S], acc0, 0, 0, 0); \
        acc1 = __builtin_amdgcn_mfma_f32_16x16x32_bf16(AF, zf[1][S], acc1, 0, 0, 0); \
        acc2 = __builtin_amdgcn_mfma_f32_16x16x32_bf16(AF, zf[2][S], acc2, 0, 0, 0); \
        acc3 = __builtin_amdgcn_mfma_f32_16x16x32_bf16(AF, zf[3][S], acc3, 0, 0, 0);
        STEP(a0, 0) STEP(a1, 1) STEP(a2, 2) STEP(a3, 3)
#undef STEP

#pragma unroll
        for (int cg = 0; cg < 4; ++cg) {
            const f32x4 a = (cg == 0) ? acc0 : (cg == 1) ? acc1
                          : (cg == 2) ? acc2 : acc3;       // cg is unroll-const
#pragma unroll
            for (int r = 0; r < 4; ++r) {
                const unsigned x = (__float_as_uint(a[r]) & 0xFFFFFC00u) | (kb + r);
                K2[cg] = umed3(K1[cg], K2[cg], x);         // new 2nd-best
                K1[cg] = umin32(K1[cg], x);                // new best
            }
        }
        kb += 16; ep += 2048; e2p += 16;
    }

    // ---- dq merge: 4 sorted-2 lists -> sorted top-4 of the 8 candidates ----
    unsigned T1[4], T2[4], T3[4], T4[4];
#pragma unroll
    for (int cg = 0; cg < 4; ++cg) {
        unsigned A1 = K1[cg], A2 = K2[cg];
        unsigned B1 = __shfl_xor(A1, 16);
        unsigned B2 = __shfl_xor(A2, 16);
        CEU(A1, B1) CEU(A2, B2) CEU(A2, B1)      // sorted4: A1,A2,B1,B2
        unsigned C1 = __shfl_xor(A1, 32);
        unsigned C2 = __shfl_xor(A2, 32);
        unsigned C3 = __shfl_xor(B1, 32);
        unsigned C4 = __shfl_xor(B2, 32);
        MRG9(A1, A2, B1, B2, C1, C2, C3, C4)
        T1[cg] = A1; T2[cg] = A2; T3[cg] = B1; T4[cg] = B2;
    }

    // lane c: column n0b + colhalf*64 + c has its list in cg' = c>>4
    {
        const int cgid = lane >> 4;
        const int c = colhalf * 64 + lane;
#define SEL4(T) ((cgid & 2) ? ((cgid & 1) ? T[3] : T[2]) : ((cgid & 1) ? T[1] : T[0]))
        kbuf[kq][c][0] = SEL4(T1);
        kbuf[kq][c][1] = SEL4(T2);
        kbuf[kq][c][2] = SEL4(T3);
        kbuf[kq][c][3] = SEL4(T4);
#undef SEL4
    }
    __syncthreads();

    // ---- waves 0,1: merge the 4 k-quarters per column, build refine lists
    if (wave < 2) {
        const int c = wave * 64 + lane;           // wave 0: cols 0-63, w1: 64-127
        unsigned A1 = kbuf[0][c][0], A2 = kbuf[0][c][1];
        unsigned A3 = kbuf[0][c][2], A4 = kbuf[0][c][3];
#pragma unroll
        for (int q = 1; q < 4; ++q) {
            unsigned B1 = kbuf[q][c][0], B2 = kbuf[q][c][1];
            unsigned B3 = kbuf[q][c][2], B4 = kbuf[q][c][3];
            MRG9(A1, A2, A3, A4, B1, B2, B3, B4)
        }
        const float M1 = __uint_as_float(A1 & 0xFFFFFC00u);
        const float M2 = __uint_as_float(A2 & 0xFFFFFC00u);
        const bool trig = (M2 - M1) < TAU;
        winner_s[c] = (int)(A1 & 0x3FFu);
        kbuf[0][c][0] = A1; kbuf[0][c][1] = A2;   // refine candidates
        kbuf[0][c][2] = A3; kbuf[0][c][3] = A4;
        const unsigned long long mask = __ballot(trig);
        if (trig) {
            const int idx = __popcll(mask & ((1ull << lane) - 1ull));
            rlist[wave * 64 + idx] = c;
        }
        if (lane == 0) {
            if (wave == 0) rcnt0 = (int)__popcll(mask);
            else           rcnt1 = (int)__popcll(mask);
        }
    }
    __syncthreads();

    // ---- cooperative exact f64 refine (~15% of columns), 8-wave stride ----
    {
        const int rc0 = rcnt0, rc1 = rcnt1;
#pragma unroll 1
        for (int seg = 0; seg < 2; ++seg) {
            const int rc = seg ? rc1 : rc0;
            const int base = seg * 64;
            for (int j = wave; j < rc; j += 8) {
                const int c = rlist[base + j];
                const int coln = n0b + c;
                const int I0 = (int)(kbuf[0][c][0] & 0x3FFu);
                const int I1 = (int)(kbuf[0][c][1] & 0x3FFu);
                const int I2 = (int)(kbuf[0][c][2] & 0x3FFu);
                const int I3 = (int)(kbuf[0][c][3] & 0x3FFu);
                double s0 = 0.0, s1 = 0.0, s2 = 0.0, s3 = 0.0;
#pragma unroll
                for (int h = 0; h < 2; ++h) {
                    const int d = h * 64 + lane;
                    const double zv = (double)zb[(size_t)d * NN + coln];
                    double q;
                    q = zv - (double)emb[(size_t)I0 * DD + d]; s0 += q * q;
                    q = zv - (double)emb[(size_t)I1 * DD + d]; s1 += q * q;
                    q = zv - (double)emb[(size_t)I2 * DD + d]; s2 += q * q;
                    q = zv - (double)emb[(size_t)I3 * DD + d]; s3 += q * q;
                }
#pragma unroll
                for (int off = 1; off < 64; off <<= 1) {
                    s0 += __shfl_xor(s0, off);
                    s1 += __shfl_xor(s1, off);
                    s2 += __shfl_xor(s2, off);
                    s3 += __shfl_xor(s3, off);
                }
                int best = I0; double db = s0;
                if (s1 < db || (s1 == db && I1 < best)) { db = s1; best = I1; }
                if (s2 < db || (s2 == db && I2 < best)) { db = s2; best = I2; }
                if (s3 < db || (s3 == db && I3 < best)) { db = s3; best = I3; }
                if (lane == 0) winner_s[c] = best;
            }
        }
    }
    __syncthreads();

    // ---- epilogue: two d-half passes through ew[128][65] (ubuf reuse) ----
    float (*ew)[65] = reinterpret_cast<float(*)[65]>(ubuf);
#pragma unroll 1
    for (int pass = 0; pass < 2; ++pass) {
        const int dbase = pass * 64;
        // stage: 128 rows, wave w rows [w*16, w*16+16); lane = d offset
#pragma unroll 4
        for (int rr = 0; rr < 16; ++rr) {
            const int r = wave * 16 + rr;
            const int idx = winner_s[r];              // wave-uniform per iter
            ew[r][lane] = emb[(size_t)idx * DD + dbase + lane];
        }
        __syncthreads();
        // write: c = tid&127 (coalesced), dgrp = tid>>7 (4 d per iter)
        {
            const int c = tid & 127;
            const int dgrp = tid >> 7;
            const int coln = n0b + c;
#pragma unroll 4
            for (int dd = 0; dd < 16; ++dd) {
                const int dl = dd * 4 + dgrp;         // 0..63 within half
                const int d  = dbase + dl;
                const float zv  = zb[(size_t)d * NN + coln];
                const float evv = ew[c][dl];
                out[((size_t)b * DD + d) * NN + coln] = zv + (evv - zv);
            }
        }
        __syncthreads();
    }
}

// ---------------------------------------------------------------------------
extern "C" void kernel_launch(void* const* d_in, const int* in_sizes, int n_in,
                              void* d_out, int out_size, void* d_ws, size_t ws_size,
                              hipStream_t stream) {
    (void)in_sizes; (void)n_in; (void)out_size; (void)ws_size;
    const float* ze  = (const float*)d_in[0];   // (B, D, N) f32
    const float* emb = (const float*)d_in[1];   // (K, D)    f32
    float*       out = (float*)d_out;           // (B, D, N) f32

    char* ws = (char*)d_ws;
    short* epk = (short*)ws;                          // 256 KB packed -2*emb
    float* e2  = (float*)(ws + (size_t)KK * DD * 2);  // 4 KB (+CADD folded)

    emb_sq_kernel<<<KK / 256, 256, 0, stream>>>(emb, e2);
    emb_pack_kernel<<<(KK * DD / 8) / 256, 256, 0, stream>>>(emb, epk);
    vq_mfma<<<(BB * NN) / 128, 512, 0, stream>>>(ze, emb, epk, e2, out);
}

// Round 21
// 44.719 us; speedup vs baseline: 1.0292x; 1.0292x over previous
//
#include <hip/hip_runtime.h>
#include <hip/hip_bf16.h>
#include <math.h>

#define BB 16
#define DD 128
#define NN 4096
#define KK 1024
// Positivity shift folded into e2': m = e2 + CADD - 2<z,e> = d^2 + (CADD - z^2).
// z^2 ~ chi2(128): max over 65k cols ~ 205 << 320 -> m > 0 always. Key quant
// at m<=~740 is <=0.125; TAU covers flip-window + quantization.
#define CADD 320.0f
#define TAU 0.45f

typedef __attribute__((ext_vector_type(8))) short short8;
typedef __attribute__((ext_vector_type(4))) float f32x4;

static __device__ __forceinline__ unsigned short f32_bf16_rne(float f) {
    unsigned u = __float_as_uint(f);
    u += 0x7FFF + ((u >> 16) & 1);
    return (unsigned short)(u >> 16);
}
static __device__ __forceinline__ unsigned umin32(unsigned a, unsigned b) { return a < b ? a : b; }
static __device__ __forceinline__ unsigned umax32(unsigned a, unsigned b) { return a > b ? a : b; }
static __device__ __forceinline__ unsigned umed3(unsigned a, unsigned b, unsigned c) {
    unsigned d;
    asm("v_med3_u32 %0, %1, %2, %3" : "=v"(d) : "v"(a), "v"(b), "v"(c));
    return d;
}

// ---------------------------------------------------------------------------
// e2'[k] = ||emb[k]||^2 + CADD  (f32)
// ---------------------------------------------------------------------------
__global__ void emb_sq_kernel(const float* __restrict__ emb,
                              float* __restrict__ e2) {
    int k = blockIdx.x * 256 + threadIdx.x;
    if (k >= KK) return;
    const float4* row = reinterpret_cast<const float4*>(emb + (size_t)k * DD);
    float a0 = 0.f, a1 = 0.f, a2 = 0.f, a3 = 0.f;
#pragma unroll
    for (int i = 0; i < DD / 16; ++i) {
        float4 v0 = row[i * 4 + 0];
        float4 v1 = row[i * 4 + 1];
        float4 v2 = row[i * 4 + 2];
        float4 v3 = row[i * 4 + 3];
        a0 += v0.x * v0.x + v0.y * v0.y + v0.z * v0.z + v0.w * v0.w;
        a1 += v1.x * v1.x + v1.y * v1.y + v1.z * v1.z + v1.w * v1.w;
        a2 += v2.x * v2.x + v2.y * v2.y + v2.z * v2.z + v2.w * v2.w;
        a3 += v3.x * v3.x + v3.y * v3.y + v3.z * v3.z + v3.w * v3.w;
    }
    e2[k] = (a0 + a1) + (a2 + a3) + CADD;
}

// ---------------------------------------------------------------------------
// Pack (-2 * emb) as SINGLE bf16 in MFMA A-fragment order (256 KB).
// Fragment (t, s, lane): k = t*16 + (lane&15), d = s*32 + (lane>>4)*8 + j.
// ---------------------------------------------------------------------------
__global__ void emb_pack_kernel(const float* __restrict__ emb,
                                short* __restrict__ epk) {
    int g = blockIdx.x * 256 + threadIdx.x;     // 16384 fragment-slots
    int lane = g & 63;
    int s    = (g >> 6) & 3;
    int t    = g >> 8;
    int k = t * 16 + (lane & 15);
    int d = s * 32 + ((lane >> 4) & 3) * 8;
    const float* src = emb + (size_t)k * DD + d;
    short8 h;
#pragma unroll
    for (int j = 0; j < 8; ++j) h[j] = (short)f32_bf16_rne(-2.0f * src[j]);
    *reinterpret_cast<short8*>(epk + (size_t)g * 8) = h;
}

// CE on packed u32 keys: a <- min, b <- max (2 VALU, no vcc)
#define CEU(a, b) { unsigned lo_ = umin32(a, b), hi_ = umax32(a, b); (a) = lo_; (b) = hi_; }
// merge two ascending-4 key lists; lowest 4 end sorted in A1..A4
#define MRG9(A1, A2, A3, A4, B1, B2, B3, B4) \
    CEU(A1, B1) CEU(A2, B2) CEU(A3, B3) CEU(A4, B4) \
    CEU(A3, B1) CEU(A4, B2) \
    CEU(A2, A3) \
    CEU(A4, B1) \
    CEU(A3, A4)

// ---------------------------------------------------------------------------
// Round-21 (zf-residency forcing): r19 geometry (wave = 64 cols x 256 k,
// block = 64 cols / 4 waves, grid 1024) with the round-20 diagnosis fixed:
// VGPR_Count=60 < zf's 64 proved the compiler was RE-READING the B-fragment
// file from LDS inside the main loop (16 ds_read_b128/tile on the MFMA
// critical path -- the ~60k-cycle both-pipes-idle stall every variant
// shared). Fix: (1) after reading zf into registers, asm volatile memory
// clobber makes LDS re-reads unsound -> zf MUST stay resident; (2) e2 staged
// to LDS (disjoint 4KB) so per-tile ev is a broadcast ds_read, not a 5th
// global load. Semantics byte-identical to r19 (absmax 0 x10).
// ---------------------------------------------------------------------------
__global__ __launch_bounds__(256, 4)
void vq_mfma(const float* __restrict__ ze, const float* __restrict__ emb,
             const short* __restrict__ epk, const float* __restrict__ e2,
             float* __restrict__ out) {
    // ubuf phases: [0,16K) zstage + [16K,20K) e2l  ->  ew[64][129] (33 KB)
    __shared__ __align__(16) char ubuf[(DD + 1) * 64 * 4];   // 33024 B
    __shared__ unsigned kbuf[4][64][4];                      // 4 KB
    __shared__ int winner_s[64];
    __shared__ int rlist[64];
    __shared__ int rcnt;

    short* zstage = reinterpret_cast<short*>(ubuf);          // 8192 shorts
    float* e2l    = reinterpret_cast<float*>(ubuf + 16384);  // 1024 f32

    const int tid  = threadIdx.x;
    const int lane = tid & 63;
    const int wave = tid >> 6;
    const int b    = blockIdx.x >> 6;             // 64 blocks per batch entry
    const int n0b  = (blockIdx.x & 63) * 64;      // block's 64-col base
    const float* zb = ze + (size_t)b * DD * NN;

    const int nq = lane & 15;
    const int dq = (lane >> 4) & 3;

    // ---- cooperative z staging (4 frag slots/thread) + e2 -> LDS ----
#pragma unroll
    for (int cg = 0; cg < 4; ++cg) {
        const int col = n0b + cg * 16 + nq;
        const int d0  = wave * 32 + dq * 8;
        const float* zp = zb + (size_t)d0 * NN + col;
        short8 h;
#pragma unroll
        for (int j = 0; j < 8; ++j) h[j] = (short)f32_bf16_rne(zp[(size_t)j * NN]);
        *reinterpret_cast<short8*>(zstage + (cg * 256 + wave * 64 + lane) * 8) = h;
    }
    *reinterpret_cast<float4*>(e2l + tid * 4) =
        *reinterpret_cast<const float4*>(e2 + tid * 4);
    __syncthreads();

    // ---- read zf frags from LDS into registers ----
    short8 zf[4][4];
#pragma unroll
    for (int cg = 0; cg < 4; ++cg)
#pragma unroll
        for (int s = 0; s < 4; ++s)
            zf[cg][s] = *reinterpret_cast<const short8*>(
                zstage + ((cg * 4 + s) * 64 + lane) * 8);
    // Memory clobber: compiler may no longer assume zstage still holds the
    // fragment values -> re-reading LDS to rematerialize zf is unsound, so
    // the 64 VGPRs of zf stay RESIDENT for the whole main loop.
    asm volatile("" ::: "memory");

    // per-cg top-2 packed keys (ascending)
    unsigned K1[4], K2[4];
#pragma unroll
    for (int cg = 0; cg < 4; ++cg) { K1[cg] = K2[cg] = 0xFFFFFFFFu; }

    const int t0 = wave * 16;                     // this wave's 16 k-tiles
    const short* ep = epk + (size_t)(t0 * 4) * 512 + (size_t)lane * 8;
    unsigned kb = (unsigned)(t0 * 16 + dq * 4);

#pragma unroll 2
    for (int tt = 0; tt < 16; ++tt) {
        const short8 a0 = *reinterpret_cast<const short8*>(ep);
        const short8 a1 = *reinterpret_cast<const short8*>(ep + 512);
        const short8 a2 = *reinterpret_cast<const short8*>(ep + 1024);
        const short8 a3 = *reinterpret_cast<const short8*>(ep + 1536);
        // e2' broadcast from LDS (CADD pre-folded)
        const float4 ev = *reinterpret_cast<const float4*>(
            e2l + (t0 + tt) * 16 + dq * 4);

        f32x4 acc0 = {ev.x, ev.y, ev.z, ev.w};
        f32x4 acc1 = acc0, acc2 = acc0, acc3 = acc0;
#define STEP(AF, S) \
        acc0 = __builtin_amdgcn_mfma_f32_16x16x32_bf16(AF, zf[0][S], acc0, 0, 0, 0); \
        acc1 = __builtin_amdgcn_mfma_f32_16x16x32_bf16(AF, zf[1][S], acc1, 0, 0, 0); \
        acc2 = __builtin_amdgcn_mfma_f32_16x16x32_bf16(AF, zf[2][S], acc2, 0, 0, 0); \
        acc3 = __builtin_amdgcn_mfma_f32_16x16x32_bf16(AF, zf[3][S], acc3, 0, 0, 0);
        STEP(a0, 0) STEP(a1, 1) STEP(a2, 2) STEP(a3, 3)
#undef STEP

#pragma unroll
        for (int cg = 0; cg < 4; ++cg) {
            const f32x4 a = (cg == 0) ? acc0 : (cg == 1) ? acc1
                          : (cg == 2) ? acc2 : acc3;       // cg is unroll-const
#pragma unroll
            for (int r = 0; r < 4; ++r) {
                const unsigned x = (__float_as_uint(a[r]) & 0xFFFFFC00u) | (kb + r);
                K2[cg] = umed3(K1[cg], K2[cg], x);         // new 2nd-best
                K1[cg] = umin32(K1[cg], x);                // new best
            }
        }
        kb += 16; ep += 2048;
    }

    // ---- dq merge: 4 sorted-2 lists -> sorted top-4 of the 8 candidates ----
    unsigned T1[4], T2[4], T3[4], T4[4];
#pragma unroll
    for (int cg = 0; cg < 4; ++cg) {
        unsigned A1 = K1[cg], A2 = K2[cg];
        unsigned B1 = __shfl_xor(A1, 16);
        unsigned B2 = __shfl_xor(A2, 16);
        CEU(A1, B1) CEU(A2, B2) CEU(A2, B1)      // sorted4: A1,A2,B1,B2
        unsigned C1 = __shfl_xor(A1, 32);
        unsigned C2 = __shfl_xor(A2, 32);
        unsigned C3 = __shfl_xor(B1, 32);
        unsigned C4 = __shfl_xor(B2, 32);
        MRG9(A1, A2, B1, B2, C1, C2, C3, C4)
        T1[cg] = A1; T2[cg] = A2; T3[cg] = B1; T4[cg] = B2;
    }

    // lane c (0..63): column n0b + c has its list in cg = c>>4 (nested-ternary
    // select: no dynamic register indexing, rule-20 safe)
    {
        const int cgid = lane >> 4;
#define SEL4(T) ((cgid & 2) ? ((cgid & 1) ? T[3] : T[2]) : ((cgid & 1) ? T[1] : T[0]))
        kbuf[wave][lane][0] = SEL4(T1);
        kbuf[wave][lane][1] = SEL4(T2);
        kbuf[wave][lane][2] = SEL4(T3);
        kbuf[wave][lane][3] = SEL4(T4);
#undef SEL4
    }
    __syncthreads();

    // ---- wave 0: merge the 4 k-quarters per column, build refine list ----
    if (wave == 0) {
        const int c = lane;                        // 64 cols, 64 lanes
        unsigned A1 = kbuf[0][c][0], A2 = kbuf[0][c][1];
        unsigned A3 = kbuf[0][c][2], A4 = kbuf[0][c][3];
#pragma unroll
        for (int q = 1; q < 4; ++q) {
            unsigned B1 = kbuf[q][c][0], B2 = kbuf[q][c][1];
            unsigned B3 = kbuf[q][c][2], B4 = kbuf[q][c][3];
            MRG9(A1, A2, A3, A4, B1, B2, B3, B4)
        }
        const float M1 = __uint_as_float(A1 & 0xFFFFFC00u);
        const float M2 = __uint_as_float(A2 & 0xFFFFFC00u);
        const bool trig = (M2 - M1) < TAU;
        winner_s[c] = (int)(A1 & 0x3FFu);
        kbuf[0][c][0] = A1; kbuf[0][c][1] = A2;   // refine candidates
        kbuf[0][c][2] = A3; kbuf[0][c][3] = A4;
        const unsigned long long mask = __ballot(trig);
        if (trig) {
            const int idx = __popcll(mask & ((1ull << lane) - 1ull));
            rlist[idx] = c;
        }
        if (lane == 0) rcnt = (int)__popcll(mask);
    }
    __syncthreads();

    // ---- cooperative exact f64 refine (~15% of columns) ----
    {
        const int rc = rcnt;
        for (int j = wave; j < rc; j += 4) {
            const int c = rlist[j];
            const int coln = n0b + c;
            const int I0 = (int)(kbuf[0][c][0] & 0x3FFu);
            const int I1 = (int)(kbuf[0][c][1] & 0x3FFu);
            const int I2 = (int)(kbuf[0][c][2] & 0x3FFu);
            const int I3 = (int)(kbuf[0][c][3] & 0x3FFu);
            double s0 = 0.0, s1 = 0.0, s2 = 0.0, s3 = 0.0;
#pragma unroll
            for (int h = 0; h < 2; ++h) {
                const int d = h * 64 + lane;
                const double zv = (double)zb[(size_t)d * NN + coln];
                double q;
                q = zv - (double)emb[(size_t)I0 * DD + d]; s0 += q * q;
                q = zv - (double)emb[(size_t)I1 * DD + d]; s1 += q * q;
                q = zv - (double)emb[(size_t)I2 * DD + d]; s2 += q * q;
                q = zv - (double)emb[(size_t)I3 * DD + d]; s3 += q * q;
            }
#pragma unroll
            for (int off = 1; off < 64; off <<= 1) {
                s0 += __shfl_xor(s0, off);
                s1 += __shfl_xor(s1, off);
                s2 += __shfl_xor(s2, off);
                s3 += __shfl_xor(s3, off);
            }
            int best = I0; double db = s0;
            if (s1 < db || (s1 == db && I1 < best)) { db = s1; best = I1; }
            if (s2 < db || (s2 == db && I2 < best)) { db = s2; best = I2; }
            if (s3 < db || (s3 == db && I3 < best)) { db = s3; best = I3; }
            if (lane == 0) winner_s[c] = best;
        }
    }
    __syncthreads();

    // ---- epilogue: stage 64 winner rows in LDS (ubuf reuse), coalesced out
    float (*ew)[DD + 1] = reinterpret_cast<float(*)[DD + 1]>(ubuf);
#pragma unroll 4
    for (int rr = 0; rr < 16; ++rr) {
        const int r = wave * 16 + rr;
        const int idx = winner_s[r];                  // wave-uniform per iter
        ew[r][lane]      = emb[(size_t)idx * DD + lane];
        ew[r][lane + 64] = emb[(size_t)idx * DD + lane + 64];
    }
    __syncthreads();

    // lane = col (64 cols); wave covers d = wave*32 .. +32
    {
        const int coln = n0b + lane;
#pragma unroll 4
        for (int dd = 0; dd < 32; ++dd) {
            const int d = wave * 32 + dd;
            const float zv = zb[(size_t)d * NN + coln];
            const float evv = ew[lane][d];
            out[((size_t)b * DD + d) * NN + coln] = zv + (evv - zv);
        }
    }
}

// ---------------------------------------------------------------------------
extern "C" void kernel_launch(void* const* d_in, const int* in_sizes, int n_in,
                              void* d_out, int out_size, void* d_ws, size_t ws_size,
                              hipStream_t stream) {
    (void)in_sizes; (void)n_in; (void)out_size; (void)ws_size;
    const float* ze  = (const float*)d_in[0];   // (B, D, N) f32
    const float* emb = (const float*)d_in[1];   // (K, D)    f32
    float*       out = (float*)d_out;           // (B, D, N) f32

    char* ws = (char*)d_ws;
    short* epk = (short*)ws;                          // 256 KB packed -2*emb
    float* e2  = (float*)(ws + (size_t)KK * DD * 2);  // 4 KB (+CADD folded)

    emb_sq_kernel<<<KK / 256, 256, 0, stream>>>(emb, e2);
    emb_pack_kernel<<<(KK * DD / 8) / 256, 256, 0, stream>>>(emb, epk);
    vq_mfma<<<(BB * NN) / 64, 256, 0, stream>>>(ze, emb, epk, e2, out);
}